// Round 5
// baseline (324.607 us; speedup 1.0000x reference)
//
#include <hip/hip_runtime.h>

// Spiking basal ganglia: T=512 sequential LIF steps, B=256 circuits.
// One wave per batch; lane i owns d1 neurons {2i,2i+1} and d2 {2i,2i+1}.
// STN/GPI populations get uniform input -> one scalar each. Means are exact
// popcounts/128 (ballot). Math is bit-identical to the R2/R3/R4 passing
// kernels (contract off, fma-contracted K=2 dots).
//
// R4 post-mortem: with plain __launch_bounds__(64) the backend targets
// default-high occupancy (~56 VGPR pressure budget) and SINKS the prefetch
// loads to their uses, collapsing the depth-8 pipeline -> ~1220 cyc/step of
// serialized HBM latency. Grid is structurally 1 wave/CU (256 blocks/256 CUs),
// so occupancy is free: __launch_bounds__(64, 1) raises the VGPR budget to
// ~512 and lets the scheduler keep the 8-step lead (~1040 cyc > 900 cyc HBM
// latency) in registers. No LDS, no barriers.

__global__ __launch_bounds__(64, 1) void bg_kernel(
    const float* __restrict__ x,      // [T,B,2]
    const float* __restrict__ dopa,   // [T,B]
    const float* __restrict__ Wd1,    // [128,2]
    const float* __restrict__ Wd2,    // [128,2]
    const float* __restrict__ nd1,    // [T,B,128]
    const float* __restrict__ nd2,    // [T,B,128]
    float* __restrict__ out)          // [T,B]
{
#pragma clang fp contract(off)
    constexpr int T = 512, B = 256;
    constexpr int D = 8;    // register prefetch depth (divides W)
    constexpr int W = 64;   // steps per window (gate latch width)

    const int b    = blockIdx.x;
    const int lane = threadIdx.x;

    const float4 w1 = *(const float4*)(Wd1 + 4 * lane);
    const float4 w2 = *(const float4*)(Wd2 + 4 * lane);

    const float* n1base = nd1 + (size_t)b * 128 + 2 * lane;
    const float* n2base = nd2 + (size_t)b * 128 + 2 * lane;
    const float* xbase  = x + (size_t)b * 2;
    const float* dbase  = dopa + b;
    constexpr size_t NSTRIDE = (size_t)B * 128;
    constexpr size_t XSTRIDE = (size_t)B * 2;

    // ---- register prefetch pipeline, depth D (unconditional assignments) ----
    float2 p1[D], p2[D], px[D];
    float  pd[D];
#pragma unroll
    for (int d = 0; d < D; ++d) {
        p1[d] = *(const float2*)(n1base + (size_t)d * NSTRIDE);
        p2[d] = *(const float2*)(n2base + (size_t)d * NSTRIDE);
        px[d] = *(const float2*)(xbase + (size_t)d * XSTRIDE);
        pd[d] = dbase[(size_t)d * B];
    }

    float v1a = 0.0f, v1b = 0.0f;
    float v2a = 0.0f, v2b = 0.0f;
    float v_stn = 0.0f, v_gpi = 0.0f;

    for (int w = 0; w < T / W; ++w) {       // 8 windows, not unrolled
        float gate_reg = 0.0f;              // lane L latches gate of step w*64+L

#pragma unroll
        for (int s = 0; s < W; ++s) {
            const int t = w * W + s;
            const int slot = s & (D - 1);   // compile-time constant per body

            const float2 n1 = p1[slot];
            const float2 n2 = p2[slot];
            const float2 xv = px[slot];
            const float  dop = pd[slot];

            // Unconditional clamped prefetch (refetching t=511 at the tail is
            // harmless; keeps every slot assigned on every path -> SROA-safe).
            int tp = t + D;
            tp = (tp < T) ? tp : (T - 1);
            p1[slot] = *(const float2*)(n1base + (size_t)tp * NSTRIDE);
            p2[slot] = *(const float2*)(n2base + (size_t)tp * NSTRIDE);
            px[slot] = *(const float2*)(xbase + (size_t)tp * XSTRIDE);
            pd[slot] = dbase[(size_t)tp * B];

            // ---- bit-identical math to the R2/R3/R4 passing kernels ----
            const float m1 = 1.0f + dop * 0.5f;
            const float m2 = 1.0f - dop * 0.3f;

            const float dot1a = __builtin_fmaf(xv.y, w1.y, xv.x * w1.x);
            const float dot1b = __builtin_fmaf(xv.y, w1.w, xv.x * w1.z);
            const float dot2a = __builtin_fmaf(xv.y, w2.y, xv.x * w2.x);
            const float dot2b = __builtin_fmaf(xv.y, w2.w, xv.x * w2.z);

            float Ia = dot1a * m1 + n1.x * 0.1f;
            float Ib = dot1b * m1 + n1.y * 0.1f;
            float Ja = dot2a * m2 + n2.x * 0.1f;
            float Jb = dot2b * m2 + n2.y * 0.1f;

            v1a = 0.8f * v1a + 0.2f * Ia;
            v1b = 0.8f * v1b + 0.2f * Ib;
            v2a = 0.8f * v2a + 0.2f * Ja;
            v2b = 0.8f * v2b + 0.2f * Jb;

            const bool s1a = v1a >= 0.5f, s1b = v1b >= 0.5f;
            const bool s2a = v2a >= 0.5f, s2b = v2b >= 0.5f;
            v1a = s1a ? 0.0f : v1a;
            v1b = s1b ? 0.0f : v1b;
            v2a = s2a ? 0.0f : v2a;
            v2b = s2b ? 0.0f : v2b;

            const int c1 = __popcll(__ballot(s1a)) + __popcll(__ballot(s1b));
            const int c2 = __popcll(__ballot(s2a)) + __popcll(__ballot(s2b));
            const float mean1 = (float)c1 * 0.0078125f;
            const float mean2 = (float)c2 * 0.0078125f;

            const float I_stn = mean2 * 0.5f;
            v_stn = 0.8f * v_stn + 0.2f * I_stn;
            const float s_stn = (v_stn >= 0.5f) ? 1.0f : 0.0f;
            v_stn = (v_stn >= 0.5f) ? 0.0f : v_stn;

            const float I_gpi = (0.4f + mean1 * -0.8f) + s_stn * 0.6f;
            v_gpi = 0.8f * v_gpi + 0.2f * I_gpi;
            const float s_gpi = (v_gpi >= 0.5f) ? 1.0f : 0.0f;
            v_gpi = (v_gpi >= 0.5f) ? 0.0f : v_gpi;

            const float gate = mean1 - s_gpi;   // wave-uniform

            // Lane s latches this step's gate (1 cndmask; s is a literal).
            gate_reg = (lane == s) ? gate : gate_reg;
        }

        // One store per window: lane L writes gate of step w*64+L.
        out[(size_t)(w * W + lane) * B + b] = gate_reg;
    }
}

extern "C" void kernel_launch(void* const* d_in, const int* in_sizes, int n_in,
                              void* d_out, int out_size, void* d_ws, size_t ws_size,
                              hipStream_t stream) {
    const float* x    = (const float*)d_in[0];
    const float* dopa = (const float*)d_in[1];
    // d_in[2] = rpe — unused by the reference
    const float* Wd1  = (const float*)d_in[3];
    const float* Wd2  = (const float*)d_in[4];
    const float* nd1  = (const float*)d_in[5];
    const float* nd2  = (const float*)d_in[6];
    float* out = (float*)d_out;

    bg_kernel<<<dim3(256), dim3(64), 0, stream>>>(x, dopa, Wd1, Wd2, nd1, nd2, out);
}

// Round 6
// 192.253 us; speedup vs baseline: 1.6884x; 1.6884x over previous
//
#include <hip/hip_runtime.h>

// Spiking basal ganglia: T=512 serial LIF steps, B=256 circuits.
// R3/R5 post-mortem: every single-wave structure is capped by per-wave memory
// concurrency (~2.7 GB/s/wave measured in R3: dur == FETCH/BW). Fix: 5 waves
// per block. Wave 0 (consumer) runs the serial recurrence; waves 1-4
// (producers) run 2 chunks ahead, loading noise with ordinary coalesced loads
// and precomputing the full input current I = (x.W)*mod + noise*0.1 with the
// EXACT op sequence of the R2..R5 passing kernels (contract off, fma dot),
// writing float4 {Ia,Ib,Ja,Jb} per consumer-lane into triple-buffered LDS.
// Consumer per step: ds_read_b128 + v-updates + ballot/popcount + stn/gpi.
// One __syncthreads per 32-step chunk; barriers bound producer latency
// exposure structurally (no reliance on compiler prefetch).

__global__ __launch_bounds__(320, 1) void bg_kernel(
    const float* __restrict__ x,      // [T,B,2]
    const float* __restrict__ dopa,   // [T,B]
    const float* __restrict__ Wd1,    // [128,2]
    const float* __restrict__ Wd2,    // [128,2]
    const float* __restrict__ nd1,    // [T,B,128]
    const float* __restrict__ nd2,    // [T,B,128]
    float* __restrict__ out)          // [T,B]
{
#pragma clang fp contract(off)
    constexpr int T = 512, B = 256;
    constexpr int S = 32;             // steps per chunk
    constexpr int NCH = T / S;        // 16 chunks
    constexpr size_t TSTRIDE = (size_t)B * 128;   // noise t-stride (floats)

    __shared__ float lds_I[3][S][64][4];   // 96 KB: triple-buffered currents
    __shared__ float lds_x[T][2];          // 4 KB
    __shared__ float lds_d[T];             // 2 KB

    const int b    = blockIdx.x;
    const int tid  = threadIdx.x;
    const int wv   = tid >> 6;        // 0 = consumer, 1..4 = producers
    const int lane = tid & 63;

    // ---- prologue A: stage x/dopa (all 320 threads) ----
    for (int t = tid; t < T; t += 320) {
        const float2 xv = *(const float2*)(x + (size_t)t * (B * 2) + b * 2);
        lds_x[t][0] = xv.x;
        lds_x[t][1] = xv.y;
        lds_d[t]    = dopa[(size_t)t * B + b];
    }
    __syncthreads();

    if (wv == 0) {
        // ================= CONSUMER =================
        __syncthreads();   // matches producers' prologue-B barrier

        float v1a = 0.0f, v1b = 0.0f;
        float v2a = 0.0f, v2b = 0.0f;
        float v_stn = 0.0f, v_gpi = 0.0f;
        float gate_reg = 0.0f;

        for (int i = 0; i < NCH; ++i) {
            const float (*buf)[64][4] = lds_I[i % 3];

#pragma unroll
            for (int s = 0; s < S; ++s) {
                const float4 I = *(const float4*)&buf[s][lane][0];

                // ---- bit-identical recurrence (R2..R5 verified) ----
                v1a = 0.8f * v1a + 0.2f * I.x;
                v1b = 0.8f * v1b + 0.2f * I.y;
                v2a = 0.8f * v2a + 0.2f * I.z;
                v2b = 0.8f * v2b + 0.2f * I.w;

                const bool s1a = v1a >= 0.5f, s1b = v1b >= 0.5f;
                const bool s2a = v2a >= 0.5f, s2b = v2b >= 0.5f;
                v1a = s1a ? 0.0f : v1a;
                v1b = s1b ? 0.0f : v1b;
                v2a = s2a ? 0.0f : v2a;
                v2b = s2b ? 0.0f : v2b;

                const int c1 = __popcll(__ballot(s1a)) + __popcll(__ballot(s1b));
                const int c2 = __popcll(__ballot(s2a)) + __popcll(__ballot(s2b));
                const float mean1 = (float)c1 * 0.0078125f;
                const float mean2 = (float)c2 * 0.0078125f;

                const float I_stn = mean2 * 0.5f;
                v_stn = 0.8f * v_stn + 0.2f * I_stn;
                const float s_stn = (v_stn >= 0.5f) ? 1.0f : 0.0f;
                v_stn = (v_stn >= 0.5f) ? 0.0f : v_stn;

                const float I_gpi = (0.4f + mean1 * -0.8f) + s_stn * 0.6f;
                v_gpi = 0.8f * v_gpi + 0.2f * I_gpi;
                const float s_gpi = (v_gpi >= 0.5f) ? 1.0f : 0.0f;
                v_gpi = (v_gpi >= 0.5f) ? 0.0f : v_gpi;

                const float gate = mean1 - s_gpi;   // wave-uniform

                // lane ((i&1)*32 + s) latches step i*32+s's gate
                const int latch = ((i & 1) << 5) | s;
                gate_reg = (lane == latch) ? gate : gate_reg;
            }

            if (i & 1) {
                // store 64 gates for steps (i-1)*32 .. i*32+31
                const int t0 = (i - 1) * S;
                out[(size_t)(t0 + lane) * B + b] = gate_reg;
            }

            __syncthreads();
        }
    } else {
        // ================= PRODUCERS (waves 1..4) =================
        const float4 w1 = *(const float4*)(Wd1 + 4 * lane);
        const float4 w2 = *(const float4*)(Wd2 + 4 * lane);
        const float* n1b = nd1 + (size_t)b * 128 + 2 * lane;
        const float* n2b = nd2 + (size_t)b * 128 + 2 * lane;
        const int p0 = wv - 1;   // this wave covers steps s = p0 + 4j, j<8

        // stage(c, bf): compute I for chunk c into lds_I[bf]
        auto stage = [&](int c, int bf) {
            const int tbase = c * S;
            float2 a1[8], a2[8];
#pragma unroll
            for (int j = 0; j < 8; ++j) {
                const int t = tbase + p0 + 4 * j;
                a1[j] = *(const float2*)(n1b + (size_t)t * TSTRIDE);
                a2[j] = *(const float2*)(n2b + (size_t)t * TSTRIDE);
            }
#pragma unroll
            for (int j = 0; j < 8; ++j) {
                const int s = p0 + 4 * j;
                const int t = tbase + s;
                const float xx = lds_x[t][0], xy = lds_x[t][1];
                const float dop = lds_d[t];

                const float m1 = 1.0f + dop * 0.5f;
                const float m2 = 1.0f - dop * 0.3f;

                const float dot1a = __builtin_fmaf(xy, w1.y, xx * w1.x);
                const float dot1b = __builtin_fmaf(xy, w1.w, xx * w1.z);
                const float dot2a = __builtin_fmaf(xy, w2.y, xx * w2.x);
                const float dot2b = __builtin_fmaf(xy, w2.w, xx * w2.z);

                float4 I;
                I.x = dot1a * m1 + a1[j].x * 0.1f;
                I.y = dot1b * m1 + a1[j].y * 0.1f;
                I.z = dot2a * m2 + a2[j].x * 0.1f;
                I.w = dot2b * m2 + a2[j].y * 0.1f;

                *(float4*)&lds_I[bf][s][lane][0] = I;
            }
        };

        // prologue B: chunks 0 and 1
        stage(0, 0);
        stage(1, 1);
        __syncthreads();

        for (int i = 0; i < NCH; ++i) {
            if (i + 2 < NCH) stage(i + 2, (i + 2) % 3);
            __syncthreads();
        }
    }
}

extern "C" void kernel_launch(void* const* d_in, const int* in_sizes, int n_in,
                              void* d_out, int out_size, void* d_ws, size_t ws_size,
                              hipStream_t stream) {
    const float* x    = (const float*)d_in[0];
    const float* dopa = (const float*)d_in[1];
    // d_in[2] = rpe — unused by the reference
    const float* Wd1  = (const float*)d_in[3];
    const float* Wd2  = (const float*)d_in[4];
    const float* nd1  = (const float*)d_in[5];
    const float* nd2  = (const float*)d_in[6];
    float* out = (float*)d_out;

    bg_kernel<<<dim3(256), dim3(320), 0, stream>>>(x, dopa, Wd1, Wd2, nd1, nd2, out);
}